// Round 2
// baseline (781.868 us; speedup 1.0000x reference)
//
#include <hip/hip_runtime.h>
#include <stdint.h>

// ---------- types ----------
typedef __bf16 bf16x8 __attribute__((ext_vector_type(8)));
typedef float f32x4 __attribute__((ext_vector_type(4)));
typedef unsigned short u16x4 __attribute__((ext_vector_type(4)));

static __device__ __forceinline__ unsigned short f2bf(float f) {
    union { float f; unsigned u; } v; v.f = f;
    unsigned r = (v.u + 0x7FFFu + ((v.u >> 16) & 1u)) >> 16;  // RNE
    return (unsigned short)r;
}

// ---------- fused prep: convert X, convert adj, transpose W0/W1/W2, zero syncs ----
// grid.x = 8192 (X) + 8192 (adj) + 768 (W transpose tiles), 256 threads
__global__ void prep_kernel(const float* __restrict__ X,
                            const float* __restrict__ adj,
                            const float* __restrict__ W0,
                            const float* __restrict__ W1,
                            const float* __restrict__ W2,
                            unsigned short* __restrict__ bufH,
                            unsigned short* __restrict__ adjB,
                            unsigned short* __restrict__ Wt,
                            unsigned* __restrict__ syncc) {
    const int bid = blockIdx.x;
    const int t = threadIdx.x;
    if (bid < 16384) {
        if (bid == 0 && t < 8) syncc[t] = 0u;   // reset grid-barrier counters
        const float* src = (bid < 8192) ? X : adj;
        unsigned short* dst = (bid < 8192) ? bufH : adjB;
        const int i = (bid & 8191) * 256 + t;
        f32x4 v = ((const f32x4*)src)[i];
        u16x4 o;
        o.x = f2bf(v.x); o.y = f2bf(v.y); o.z = f2bf(v.z); o.w = f2bf(v.w);
        ((u16x4*)dst)[i] = o;
    } else {
        const int wb = bid - 16384;          // 0..767
        const int z = wb >> 8;               // which W
        const int tile = wb & 255;           // 16x16 tiles of 32x32
        const float* W = (z == 0) ? W0 : (z == 1) ? W1 : W2;
        unsigned short* out = Wt + (size_t)z * (512 * 512);
        __shared__ float tileS[32][33];
        const int bx = (tile & 15) * 32, by = (tile >> 4) * 32;
        const int tx = t & 31, ty = t >> 5;  // 32 x 8
        #pragma unroll
        for (int r = 0; r < 32; r += 8)
            tileS[ty + r][tx] = W[(size_t)(by + ty + r) * 512 + (bx + tx)];
        __syncthreads();
        #pragma unroll
        for (int r = 0; r < 32; r += 8)
            out[(size_t)(bx + ty + r) * 512 + (by + tx)] = f2bf(tileS[tx][ty + r]);
    }
}

// ---------- grid-wide barrier for 512 co-resident blocks ----------
// Per-sync-point counter (no generation logic); prep zeroes them each launch.
static __device__ __forceinline__ void gsync(unsigned* __restrict__ cnt) {
    __syncthreads();
    __threadfence();                         // release: drain + make stores visible (agent scope)
    if (threadIdx.x == 0) {
        atomicAdd(cnt, 1u);                  // device-scope by default
        while (__hip_atomic_load(cnt, __ATOMIC_RELAXED, __HIP_MEMORY_SCOPE_AGENT) < 512u)
            __builtin_amdgcn_s_sleep(2);
    }
    __syncthreads();
    __threadfence();                         // acquire: invalidate stale L1/L2 lines
}

// ---------- one GEMM stage: D[m][n] = sum_k A[m*LDA+k]*B[n*LDB+k]; out[n*LDO+m]
// 128x128 tile, BK=64 double-buffered, counted-vmcnt pipeline (T3/T4):
// steady state keeps 16 global_load_lds in flight; waits vmcnt(8) for the
// buffer about to be computed; raw s_barrier (no implicit drain);
// lgkmcnt(0)+sched_barrier before the reuse barrier (rule #18); setprio on MFMA.
// LDS swizzle: 16B chunks, 8/row, chunk(row,pos) at row*8 + (pos ^ (row&7)).
template<int LDA, int LDB, int LDO, bool BIAS, bool RELU, typename OT>
static __device__ __forceinline__
void gemm_stage(const unsigned short* __restrict__ A,
                const unsigned short* __restrict__ B,
                OT* __restrict__ out, const float* __restrict__ bias,
                int m0, int n0,
                unsigned short (*As)[128 * 64], unsigned short (*Bs)[128 * 64]) {
    const int tid  = threadIdx.x;
    const int lane = tid & 63;
    const int wave = tid >> 6;
    const int quad = lane >> 4;
    const int l16  = lane & 15;
    const int wm   = wave & 1;
    const int wn   = wave >> 1;

    const int trow8 = tid >> 3;                   // 0..31
    const int tpos8 = (tid & 7) ^ (trow8 & 7);    // r-independent swizzled pos
    const unsigned short* aG = A + (size_t)(m0 + trow8) * LDA + tpos8 * 8;
    const unsigned short* bG = B + (size_t)(n0 + trow8) * LDB + tpos8 * 8;

    f32x4 acc[4][4];
    #pragma unroll
    for (int i = 0; i < 4; ++i)
        #pragma unroll
        for (int j = 0; j < 4; ++j) {
            f32x4 z = {0.f, 0.f, 0.f, 0.f};
            acc[i][j] = z;
        }

#define STAGE(buf, ko)                                                         \
    do {                                                                       \
        char* aL = (char*)(As[buf]) + tid * 16;                                \
        char* bL = (char*)(Bs[buf]) + tid * 16;                                \
        _Pragma("unroll")                                                      \
        for (int r = 0; r < 4; ++r)                                            \
            __builtin_amdgcn_global_load_lds(                                  \
                (__attribute__((address_space(1))) void*)(uintptr_t)(aG + (size_t)(r * 32) * LDA + (ko)), \
                (__attribute__((address_space(3))) void*)(aL + r * 4096), 16, 0, 0); \
        _Pragma("unroll")                                                      \
        for (int r = 0; r < 4; ++r)                                            \
            __builtin_amdgcn_global_load_lds(                                  \
                (__attribute__((address_space(1))) void*)(uintptr_t)(bG + (size_t)(r * 32) * LDB + (ko)), \
                (__attribute__((address_space(3))) void*)(bL + r * 4096), 16, 0, 0); \
    } while (0)

#define COMPUTE(buf)                                                           \
    do {                                                                       \
        _Pragma("unroll")                                                      \
        for (int ks = 0; ks < 2; ++ks) {                                       \
            bf16x8 af[4], bfr[4];                                              \
            _Pragma("unroll")                                                  \
            for (int i = 0; i < 4; ++i) {                                      \
                const int row = wm * 64 + i * 16 + l16;                        \
                const int idx = row * 8 + ((ks * 4 + quad) ^ (row & 7));       \
                af[i] = *(const bf16x8*)((const char*)(As[buf]) + idx * 16);   \
            }                                                                  \
            _Pragma("unroll")                                                  \
            for (int j = 0; j < 4; ++j) {                                      \
                const int row = wn * 64 + j * 16 + l16;                        \
                const int idx = row * 8 + ((ks * 4 + quad) ^ (row & 7));       \
                bfr[j] = *(const bf16x8*)((const char*)(Bs[buf]) + idx * 16);  \
            }                                                                  \
            _Pragma("unroll")                                                  \
            for (int i = 0; i < 4; ++i)                                        \
                _Pragma("unroll")                                              \
                for (int j = 0; j < 4; ++j)                                    \
                    acc[i][j] = __builtin_amdgcn_mfma_f32_16x16x32_bf16(af[i], bfr[j], acc[i][j], 0, 0, 0); \
        }                                                                      \
    } while (0)

    STAGE(0, 0);     // t0 -> buf0
    STAGE(1, 64);    // t1 -> buf1   (16 loads in flight)

    #pragma unroll 1
    for (int kp = 0; kp < 4; ++kp) {       // K = 512 = 4 x (two 64-halves)
        const int ko = kp * 128;
        // ---- half A: buf0 (k = ko) ----
        asm volatile("s_waitcnt vmcnt(8)" ::: "memory");   // buf0's 8 loads done
        __builtin_amdgcn_s_barrier();                      // all waves agree
        __builtin_amdgcn_s_setprio(1);
        COMPUTE(0);
        __builtin_amdgcn_s_setprio(0);
        asm volatile("s_waitcnt lgkmcnt(0)" ::: "memory"); // my ds_reads of buf0 done
        __builtin_amdgcn_sched_barrier(0);
        __builtin_amdgcn_s_barrier();                      // all waves done reading buf0
        if (kp < 3) STAGE(0, ko + 128);                    // refill buf0 (in-flight: 16)
        // ---- half B: buf1 (k = ko + 64) ----
        if (kp < 3) asm volatile("s_waitcnt vmcnt(8)" ::: "memory");
        else        asm volatile("s_waitcnt vmcnt(0)" ::: "memory");
        __builtin_amdgcn_s_barrier();
        __builtin_amdgcn_s_setprio(1);
        COMPUTE(1);
        __builtin_amdgcn_s_setprio(0);
        asm volatile("s_waitcnt lgkmcnt(0)" ::: "memory");
        __builtin_amdgcn_sched_barrier(0);
        __builtin_amdgcn_s_barrier();
        if (kp < 3) STAGE(1, ko + 192);
    }
#undef STAGE
#undef COMPUTE

    // epilogue: C/D layout col=l16 (n-dim), row=quad*4+reg (m-dim); write out[n*LDO+m]
    #pragma unroll
    for (int i = 0; i < 4; ++i) {
        const int mb = m0 + wm * 64 + i * 16 + quad * 4;
        f32x4 bb = {0.f, 0.f, 0.f, 0.f};
        if constexpr (BIAS) bb = *(const f32x4*)(bias + mb);
        #pragma unroll
        for (int j = 0; j < 4; ++j) {
            const int n = n0 + wn * 64 + j * 16 + l16;
            f32x4 v = acc[i][j];
            if constexpr (BIAS) v += bb;
            if constexpr (RELU) {
                v.x = v.x > 0.f ? v.x : 0.f;
                v.y = v.y > 0.f ? v.y : 0.f;
                v.z = v.z > 0.f ? v.z : 0.f;
                v.w = v.w > 0.f ? v.w : 0.f;
            }
            if constexpr (sizeof(OT) == 4) {
                *(f32x4*)((float*)out + (size_t)n * LDO + mb) = v;
            } else {
                u16x4 o;
                o.x = f2bf(v.x); o.y = f2bf(v.y); o.z = f2bf(v.z); o.w = f2bf(v.w);
                *(u16x4*)((unsigned short*)out + (size_t)n * LDO + mb) = o;
            }
        }
    }
}

// ---------- fused GCN: 6 GEMM stages, 5 grid barriers, one persistent launch ----
// 512 blocks x 256 threads = exactly 2 blocks/CU on 256 CUs (LDS 64KB/block
// fits 2x in 160KB; launch_bounds caps VGPR for 2 waves/SIMD) -> all blocks
// co-resident, so the atomic grid barrier cannot deadlock.
__global__ __launch_bounds__(256, 2)
void gcn_fused(unsigned short* __restrict__ bufH,
               unsigned short* __restrict__ tmpT,
               const unsigned short* __restrict__ adjB,
               const unsigned short* __restrict__ Wt,
               const float* __restrict__ b0, const float* __restrict__ b1,
               const float* __restrict__ b2, float* __restrict__ out,
               unsigned* __restrict__ syncc) {
    __shared__ unsigned short As[2][128 * 64];   // 2 x 16 KB
    __shared__ unsigned short Bs[2][128 * 64];   // 2 x 16 KB

    const int bid = blockIdx.x;
    // feature-GEMM mapping: M=16384 (nodes), N=512 (features)
    const int tm0 = (bid & 127) * 128;
    const int tn0 = (bid >> 7) * 128;
    // adj-GEMM mapping: per-z 512x512, 4x4 blocks, z = bid>>4
    const int am0 = (bid & 3) * 128;
    const int an0 = ((bid >> 2) & 3) * 128;
    const long z  = bid >> 4;
    const unsigned short* Az = tmpT + z * 512;        // tmpT[e][z*512 + node]
    const unsigned short* Bz = adjB + z * 262144;
    unsigned short* Hz = bufH + z * 262144;
    float* Oz = out + z * 262144;

    // layer 0
    gemm_stage<512, 512, 16384, false, false, unsigned short>(bufH, Wt, tmpT, nullptr, tm0, tn0, As, Bs);
    gsync(syncc + 0);
    gemm_stage<16384, 512, 512, true, true, unsigned short>(Az, Bz, Hz, b0, am0, an0, As, Bs);
    gsync(syncc + 1);
    // layer 1
    gemm_stage<512, 512, 16384, false, false, unsigned short>(bufH, Wt + 262144, tmpT, nullptr, tm0, tn0, As, Bs);
    gsync(syncc + 2);
    gemm_stage<16384, 512, 512, true, true, unsigned short>(Az, Bz, Hz, b1, am0, an0, As, Bs);
    gsync(syncc + 3);
    // layer 2 (no relu, fp32 out)
    gemm_stage<512, 512, 16384, false, false, unsigned short>(bufH, Wt + 2 * 262144, tmpT, nullptr, tm0, tn0, As, Bs);
    gsync(syncc + 4);
    gemm_stage<16384, 512, 512, true, false, float>(Az, Bz, Oz, b2, am0, an0, As, Bs);
}

extern "C" void kernel_launch(void* const* d_in, const int* in_sizes, int n_in,
                              void* d_out, int out_size, void* d_ws, size_t ws_size,
                              hipStream_t stream) {
    (void)in_sizes; (void)n_in; (void)out_size; (void)ws_size;
    const float* X   = (const float*)d_in[0];
    const float* adj = (const float*)d_in[1];
    const float* W0  = (const float*)d_in[2];
    const float* b0  = (const float*)d_in[3];
    const float* W1  = (const float*)d_in[4];
    const float* b1  = (const float*)d_in[5];
    const float* W2  = (const float*)d_in[6];
    const float* b2  = (const float*)d_in[7];
    float* out = (float*)d_out;

    // workspace layout (bf16): adjB | bufH (node-major) | tmpT (feat-major) | Wt x3 | sync
    char* ws = (char*)d_ws;
    const size_t SZ = 16777216;  // 32*512*512*2
    unsigned short* adjB = (unsigned short*)(ws);
    unsigned short* bufH = (unsigned short*)(ws + SZ);
    unsigned short* tmpT = (unsigned short*)(ws + 2 * SZ);
    unsigned short* Wt   = (unsigned short*)(ws + 3 * SZ);
    unsigned*       sync = (unsigned*)(ws + 3 * SZ + 4 * 1024 * 1024);

    prep_kernel<<<16384 + 768, 256, 0, stream>>>(X, adj, W0, W1, W2, bufH, adjB, Wt, sync);
    gcn_fused<<<512, 256, 0, stream>>>(bufH, tmpT, adjB, Wt, b0, b1, b2, out, sync);
}

// Round 3
// 228.534 us; speedup vs baseline: 3.4212x; 3.4212x over previous
//
#include <hip/hip_runtime.h>
#include <stdint.h>

// ---------- types ----------
typedef __bf16 bf16x8 __attribute__((ext_vector_type(8)));
typedef float f32x4 __attribute__((ext_vector_type(4)));
typedef unsigned short u16x4 __attribute__((ext_vector_type(4)));

static __device__ __forceinline__ unsigned short f2bf(float f) {
    union { float f; unsigned u; } v; v.f = f;
    unsigned r = (v.u + 0x7FFFu + ((v.u >> 16) & 1u)) >> 16;  // RNE
    return (unsigned short)r;
}

// ---------- fused prep: convert X, convert adj, transpose W0/W1/W2 ----------
// grid.x = 8192 (X) + 8192 (adj) + 768 (W transpose tiles), 256 threads
__global__ void prep_kernel(const float* __restrict__ X,
                            const float* __restrict__ adj,
                            const float* __restrict__ W0,
                            const float* __restrict__ W1,
                            const float* __restrict__ W2,
                            unsigned short* __restrict__ bufH,
                            unsigned short* __restrict__ adjB,
                            unsigned short* __restrict__ Wt) {
    const int bid = blockIdx.x;
    const int t = threadIdx.x;
    if (bid < 16384) {
        const float* src = (bid < 8192) ? X : adj;
        unsigned short* dst = (bid < 8192) ? bufH : adjB;
        const int i = (bid & 8191) * 256 + t;
        f32x4 v = ((const f32x4*)src)[i];
        u16x4 o;
        o.x = f2bf(v.x); o.y = f2bf(v.y); o.z = f2bf(v.z); o.w = f2bf(v.w);
        ((u16x4*)dst)[i] = o;
    } else {
        const int wb = bid - 16384;          // 0..767
        const int z = wb >> 8;               // which W
        const int tile = wb & 255;           // 16x16 tiles of 32x32
        const float* W = (z == 0) ? W0 : (z == 1) ? W1 : W2;
        unsigned short* out = Wt + (size_t)z * (512 * 512);
        __shared__ float tileS[32][33];
        const int bx = (tile & 15) * 32, by = (tile >> 4) * 32;
        const int tx = t & 31, ty = t >> 5;  // 32 x 8
        #pragma unroll
        for (int r = 0; r < 32; r += 8)
            tileS[ty + r][tx] = W[(size_t)(by + ty + r) * 512 + (bx + tx)];
        __syncthreads();
        #pragma unroll
        for (int r = 0; r < 32; r += 8)
            out[(size_t)(bx + ty + r) * 512 + (by + tx)] = f2bf(tileS[tx][ty + r]);
    }
}

// ---------- GEMM: D[m][n] = sum_k A[m*LDA+k]*B[n*LDB+k]; writes out[n*LDO+m]
// 128x128 tile, BK=64 double-buffered, counted-vmcnt pipeline (T3/T4):
// steady state keeps 16 global_load_lds in flight; each wave waits vmcnt(8)
// (its own 8 loads for the buffer about to be computed) THEN raw s_barrier --
// collective readiness without draining the other buffer's prefetch.
// lgkmcnt(0)+sched_barrier(0) before the reuse barrier (rule #18);
// s_setprio(1) around the MFMA cluster (T5).
// LDS swizzle: 16B chunks, 8/row, chunk(row,pos) at row*8 + (pos ^ (row&7)).
// Staging thread t: row = t>>3, pos = (t&7)^((t>>3)&7) (r-independent).
template<int LDA, int LDB, int LDO, bool BIAS, bool RELU, typename OT>
__global__ __launch_bounds__(256, 2)
void gemm_abT_ct(const unsigned short* __restrict__ A,
                 const unsigned short* __restrict__ B,
                 OT* __restrict__ out, const float* __restrict__ bias,
                 long batchA, long batchB, long batchO) {
    __shared__ unsigned short As[2][128 * 64];   // 2 x 16 KB
    __shared__ unsigned short Bs[2][128 * 64];   // 2 x 16 KB

    const int tid  = threadIdx.x;
    const int lane = tid & 63;
    const int wave = tid >> 6;
    const int quad = lane >> 4;
    const int l16  = lane & 15;
    const int wm   = wave & 1;
    const int wn   = wave >> 1;

    const int m0 = blockIdx.x * 128;
    const int n0 = blockIdx.y * 128;
    A   += (size_t)blockIdx.z * batchA;
    B   += (size_t)blockIdx.z * batchB;
    out += (size_t)blockIdx.z * batchO;

    const int trow8 = tid >> 3;                   // 0..31
    const int tpos8 = (tid & 7) ^ (trow8 & 7);    // r-independent swizzled pos
    const unsigned short* aG = A + (size_t)(m0 + trow8) * LDA + tpos8 * 8;
    const unsigned short* bG = B + (size_t)(n0 + trow8) * LDB + tpos8 * 8;

    f32x4 acc[4][4];
    #pragma unroll
    for (int i = 0; i < 4; ++i)
        #pragma unroll
        for (int j = 0; j < 4; ++j) {
            f32x4 z = {0.f, 0.f, 0.f, 0.f};
            acc[i][j] = z;
        }

#define STAGE(buf, ko)                                                         \
    do {                                                                       \
        char* aL = (char*)(As[buf]) + tid * 16;                                \
        char* bL = (char*)(Bs[buf]) + tid * 16;                                \
        _Pragma("unroll")                                                      \
        for (int r = 0; r < 4; ++r)                                            \
            __builtin_amdgcn_global_load_lds(                                  \
                (__attribute__((address_space(1))) void*)(uintptr_t)(aG + (size_t)(r * 32) * LDA + (ko)), \
                (__attribute__((address_space(3))) void*)(aL + r * 4096), 16, 0, 0); \
        _Pragma("unroll")                                                      \
        for (int r = 0; r < 4; ++r)                                            \
            __builtin_amdgcn_global_load_lds(                                  \
                (__attribute__((address_space(1))) void*)(uintptr_t)(bG + (size_t)(r * 32) * LDB + (ko)), \
                (__attribute__((address_space(3))) void*)(bL + r * 4096), 16, 0, 0); \
    } while (0)

#define COMPUTE(buf)                                                           \
    do {                                                                       \
        _Pragma("unroll")                                                      \
        for (int ks = 0; ks < 2; ++ks) {                                       \
            bf16x8 af[4], bfr[4];                                              \
            _Pragma("unroll")                                                  \
            for (int i = 0; i < 4; ++i) {                                      \
                const int row = wm * 64 + i * 16 + l16;                        \
                const int idx = row * 8 + ((ks * 4 + quad) ^ (row & 7));       \
                af[i] = *(const bf16x8*)((const char*)(As[buf]) + idx * 16);   \
            }                                                                  \
            _Pragma("unroll")                                                  \
            for (int j = 0; j < 4; ++j) {                                      \
                const int row = wn * 64 + j * 16 + l16;                        \
                const int idx = row * 8 + ((ks * 4 + quad) ^ (row & 7));       \
                bfr[j] = *(const bf16x8*)((const char*)(Bs[buf]) + idx * 16);  \
            }                                                                  \
            _Pragma("unroll")                                                  \
            for (int i = 0; i < 4; ++i)                                        \
                _Pragma("unroll")                                              \
                for (int j = 0; j < 4; ++j)                                    \
                    acc[i][j] = __builtin_amdgcn_mfma_f32_16x16x32_bf16(af[i], bfr[j], acc[i][j], 0, 0, 0); \
        }                                                                      \
    } while (0)

    STAGE(0, 0);     // -> buf0
    STAGE(1, 64);    // -> buf1   (16 loads in flight)

    #pragma unroll 1
    for (int kp = 0; kp < 4; ++kp) {       // K = 512 = 4 x (two 64-halves)
        const int ko = kp * 128;
        // ---- half A: buf0 (k = ko) ----
        asm volatile("s_waitcnt vmcnt(8)" ::: "memory");   // my buf0 loads done
        __builtin_amdgcn_s_barrier();                      // all waves ready
        __builtin_amdgcn_s_setprio(1);
        COMPUTE(0);
        __builtin_amdgcn_s_setprio(0);
        asm volatile("s_waitcnt lgkmcnt(0)" ::: "memory"); // my ds_reads of buf0 done
        __builtin_amdgcn_sched_barrier(0);
        __builtin_amdgcn_s_barrier();                      // all waves done reading buf0
        if (kp < 3) STAGE(0, ko + 128);                    // refill buf0 (in flight: 16)
        // ---- half B: buf1 (k = ko + 64) ----
        if (kp < 3) asm volatile("s_waitcnt vmcnt(8)" ::: "memory");
        else        asm volatile("s_waitcnt vmcnt(0)" ::: "memory");
        __builtin_amdgcn_s_barrier();
        __builtin_amdgcn_s_setprio(1);
        COMPUTE(1);
        __builtin_amdgcn_s_setprio(0);
        asm volatile("s_waitcnt lgkmcnt(0)" ::: "memory");
        __builtin_amdgcn_sched_barrier(0);
        __builtin_amdgcn_s_barrier();
        if (kp < 3) STAGE(1, ko + 192);
    }
#undef STAGE
#undef COMPUTE

    // epilogue: C/D layout col=l16 (n-dim), row=quad*4+reg (m-dim); write out[n*LDO+m]
    #pragma unroll
    for (int i = 0; i < 4; ++i) {
        const int mb = m0 + wm * 64 + i * 16 + quad * 4;
        f32x4 bb = {0.f, 0.f, 0.f, 0.f};
        if constexpr (BIAS) bb = *(const f32x4*)(bias + mb);
        #pragma unroll
        for (int j = 0; j < 4; ++j) {
            const int n = n0 + wn * 64 + j * 16 + l16;
            f32x4 v = acc[i][j];
            if constexpr (BIAS) v += bb;
            if constexpr (RELU) {
                v.x = v.x > 0.f ? v.x : 0.f;
                v.y = v.y > 0.f ? v.y : 0.f;
                v.z = v.z > 0.f ? v.z : 0.f;
                v.w = v.w > 0.f ? v.w : 0.f;
            }
            if constexpr (sizeof(OT) == 4) {
                *(f32x4*)((float*)out + (size_t)n * LDO + mb) = v;
            } else {
                u16x4 o;
                o.x = f2bf(v.x); o.y = f2bf(v.y); o.z = f2bf(v.z); o.w = f2bf(v.w);
                *(u16x4*)((unsigned short*)out + (size_t)n * LDO + mb) = o;
            }
        }
    }
}

extern "C" void kernel_launch(void* const* d_in, const int* in_sizes, int n_in,
                              void* d_out, int out_size, void* d_ws, size_t ws_size,
                              hipStream_t stream) {
    (void)in_sizes; (void)n_in; (void)out_size; (void)ws_size;
    const float* X   = (const float*)d_in[0];
    const float* adj = (const float*)d_in[1];
    const float* W0  = (const float*)d_in[2];
    const float* b0  = (const float*)d_in[3];
    const float* W1  = (const float*)d_in[4];
    const float* b1  = (const float*)d_in[5];
    const float* W2  = (const float*)d_in[6];
    const float* b2  = (const float*)d_in[7];
    float* out = (float*)d_out;

    // workspace layout (bf16): adjB | bufH (X/h, node-major) | tmpT (feat-major) | Wt x3
    char* ws = (char*)d_ws;
    const size_t SZ = 16777216;  // 32*512*512*2
    unsigned short* adjB = (unsigned short*)(ws);
    unsigned short* bufH = (unsigned short*)(ws + SZ);
    unsigned short* tmpT = (unsigned short*)(ws + 2 * SZ);
    unsigned short* Wt   = (unsigned short*)(ws + 3 * SZ);
    const unsigned short* W0t = Wt;
    const unsigned short* W1t = Wt + 262144;
    const unsigned short* W2t = Wt + 2 * 262144;

    prep_kernel<<<16384 + 768, 256, 0, stream>>>(X, adj, W0, W1, W2, bufH, adjB, Wt);

    const long BATCH = 512L * 512L;

    // layer 0: tmpT[e][node] = (h @ W0);  h = relu(adj @ tmp + b0) node-major
    gemm_abT_ct<512, 512, 16384, false, false, unsigned short>
        <<<dim3(128, 4, 1), 256, 0, stream>>>(bufH, W0t, tmpT, nullptr, 0, 0, 0);
    gemm_abT_ct<16384, 512, 512, true, true, unsigned short>
        <<<dim3(4, 4, 32), 256, 0, stream>>>(tmpT, adjB, bufH, b0, 512, BATCH, BATCH);
    // layer 1
    gemm_abT_ct<512, 512, 16384, false, false, unsigned short>
        <<<dim3(128, 4, 1), 256, 0, stream>>>(bufH, W1t, tmpT, nullptr, 0, 0, 0);
    gemm_abT_ct<16384, 512, 512, true, true, unsigned short>
        <<<dim3(4, 4, 32), 256, 0, stream>>>(tmpT, adjB, bufH, b1, 512, BATCH, BATCH);
    // layer 2 (no relu, fp32 out)
    gemm_abT_ct<512, 512, 16384, false, false, unsigned short>
        <<<dim3(128, 4, 1), 256, 0, stream>>>(bufH, W2t, tmpT, nullptr, 0, 0, 0);
    gemm_abT_ct<16384, 512, 512, true, false, float>
        <<<dim3(4, 4, 32), 256, 0, stream>>>(tmpT, adjB, out, b2, 512, BATCH, BATCH);
}

// Round 4
// 212.981 us; speedup vs baseline: 3.6711x; 1.0730x over previous
//
#include <hip/hip_runtime.h>
#include <stdint.h>

// ---------- types ----------
typedef __bf16 bf16x8 __attribute__((ext_vector_type(8)));
typedef float f32x4 __attribute__((ext_vector_type(4)));
typedef unsigned short u16x4 __attribute__((ext_vector_type(4)));

static __device__ __forceinline__ unsigned short f2bf(float f) {
    union { float f; unsigned u; } v; v.f = f;
    unsigned r = (v.u + 0x7FFFu + ((v.u >> 16) & 1u)) >> 16;  // RNE
    return (unsigned short)r;
}

// ---------- fused prep: convert X, convert adj, transpose W0/W1/W2 ----------
// grid.x = 8192 (X) + 8192 (adj) + 768 (W transpose tiles), 256 threads
__global__ void prep_kernel(const float* __restrict__ X,
                            const float* __restrict__ adj,
                            const float* __restrict__ W0,
                            const float* __restrict__ W1,
                            const float* __restrict__ W2,
                            unsigned short* __restrict__ bufH,
                            unsigned short* __restrict__ adjB,
                            unsigned short* __restrict__ Wt) {
    const int bid = blockIdx.x;
    const int t = threadIdx.x;
    if (bid < 16384) {
        const float* src = (bid < 8192) ? X : adj;
        unsigned short* dst = (bid < 8192) ? bufH : adjB;
        const int i = (bid & 8191) * 256 + t;
        f32x4 v = ((const f32x4*)src)[i];
        u16x4 o;
        o.x = f2bf(v.x); o.y = f2bf(v.y); o.z = f2bf(v.z); o.w = f2bf(v.w);
        ((u16x4*)dst)[i] = o;
    } else {
        const int wb = bid - 16384;          // 0..767
        const int z = wb >> 8;               // which W
        const int tile = wb & 255;           // 16x16 tiles of 32x32
        const float* W = (z == 0) ? W0 : (z == 1) ? W1 : W2;
        unsigned short* out = Wt + (size_t)z * (512 * 512);
        __shared__ float tileS[32][33];
        const int bx = (tile & 15) * 32, by = (tile >> 4) * 32;
        const int tx = t & 31, ty = t >> 5;  // 32 x 8
        #pragma unroll
        for (int r = 0; r < 32; r += 8)
            tileS[ty + r][tx] = W[(size_t)(by + ty + r) * 512 + (bx + tx)];
        __syncthreads();
        #pragma unroll
        for (int r = 0; r < 32; r += 8)
            out[(size_t)(bx + ty + r) * 512 + (by + tx)] = f2bf(tileS[tx][ty + r]);
    }
}

// ---------- GEMM: D[m][n] = sum_k A[m*LDA+k]*B[n*LDB+k]; writes out[n*LDO+m]
// 128x128 tile, BK=64 double-buffered, counted-vmcnt pipeline (unchanged from
// round 3). NEW this round: 1-D grid of 512 blocks with XCD-AFFINITY decode
// (hardware round-robins linear block id across the 8 XCDs; per-XCD L2s are
// not shared, so co-locate blocks that share operand slabs):
//  - ADJ mode:  XCD x = L&7 owns z in {x, x+8, x+16, x+24}; all 16 tiles of a
//    z on one XCD -> per-z A/B slabs (1 MB) become L2-resident.
//  - FEAT mode: XCD x owns m-rows [x*2048,(x+1)*2048); the 4 n-tiles sharing
//    an A-slab are on the same XCD -> A fetched once per XCD (2 MB, L2-fits).
// LDS swizzle: 16B chunks, 8/row, chunk(row,pos) at row*8 + (pos ^ (row&7)).
template<int LDA, int LDB, int LDO, bool BIAS, bool RELU, bool ADJ, typename OT>
__global__ __launch_bounds__(256, 2)
void gemm_abT_ct(const unsigned short* __restrict__ A,
                 const unsigned short* __restrict__ B,
                 OT* __restrict__ out, const float* __restrict__ bias,
                 long batchA, long batchB, long batchO) {
    __shared__ unsigned short As[2][128 * 64];   // 2 x 16 KB
    __shared__ unsigned short Bs[2][128 * 64];   // 2 x 16 KB

    const int tid  = threadIdx.x;
    const int lane = tid & 63;
    const int wave = tid >> 6;
    const int quad = lane >> 4;
    const int l16  = lane & 15;
    const int wm   = wave & 1;
    const int wn   = wave >> 1;

    // ---- XCD-affinity decode (bijective over 512 blocks; 512 % 8 == 0) ----
    const int L = blockIdx.x;
    const int x = L & 7;        // XCD id (hw round-robin on linear block id)
    const int j = L >> 3;       // 0..63 within XCD
    int m0, n0;
    long z;
    if constexpr (ADJ) {
        z = x + 8 * (j >> 4);             // 4 z's per XCD
        const int t4 = j & 15;            // 16 tiles of this z
        m0 = (t4 & 3) * 128;
        n0 = (t4 >> 2) * 128;
    } else {
        z = 0;
        m0 = (x * 16 + (j >> 2)) * 128;   // XCD x owns 16 consecutive m-tiles
        n0 = (j & 3) * 128;
    }
    A   += (size_t)z * batchA;
    B   += (size_t)z * batchB;
    out += (size_t)z * batchO;

    const int trow8 = tid >> 3;                   // 0..31
    const int tpos8 = (tid & 7) ^ (trow8 & 7);    // r-independent swizzled pos
    const unsigned short* aG = A + (size_t)(m0 + trow8) * LDA + tpos8 * 8;
    const unsigned short* bG = B + (size_t)(n0 + trow8) * LDB + tpos8 * 8;

    f32x4 acc[4][4];
    #pragma unroll
    for (int i = 0; i < 4; ++i)
        #pragma unroll
        for (int j2 = 0; j2 < 4; ++j2) {
            f32x4 zz = {0.f, 0.f, 0.f, 0.f};
            acc[i][j2] = zz;
        }

#define STAGE(buf, ko)                                                         \
    do {                                                                       \
        char* aL = (char*)(As[buf]) + tid * 16;                                \
        char* bL = (char*)(Bs[buf]) + tid * 16;                                \
        _Pragma("unroll")                                                      \
        for (int r = 0; r < 4; ++r)                                            \
            __builtin_amdgcn_global_load_lds(                                  \
                (__attribute__((address_space(1))) void*)(uintptr_t)(aG + (size_t)(r * 32) * LDA + (ko)), \
                (__attribute__((address_space(3))) void*)(aL + r * 4096), 16, 0, 0); \
        _Pragma("unroll")                                                      \
        for (int r = 0; r < 4; ++r)                                            \
            __builtin_amdgcn_global_load_lds(                                  \
                (__attribute__((address_space(1))) void*)(uintptr_t)(bG + (size_t)(r * 32) * LDB + (ko)), \
                (__attribute__((address_space(3))) void*)(bL + r * 4096), 16, 0, 0); \
    } while (0)

#define COMPUTE(buf)                                                           \
    do {                                                                       \
        _Pragma("unroll")                                                      \
        for (int ks = 0; ks < 2; ++ks) {                                       \
            bf16x8 af[4], bfr[4];                                              \
            _Pragma("unroll")                                                  \
            for (int i = 0; i < 4; ++i) {                                      \
                const int row = wm * 64 + i * 16 + l16;                        \
                const int idx = row * 8 + ((ks * 4 + quad) ^ (row & 7));       \
                af[i] = *(const bf16x8*)((const char*)(As[buf]) + idx * 16);   \
            }                                                                  \
            _Pragma("unroll")                                                  \
            for (int j2 = 0; j2 < 4; ++j2) {                                   \
                const int row = wn * 64 + j2 * 16 + l16;                       \
                const int idx = row * 8 + ((ks * 4 + quad) ^ (row & 7));       \
                bfr[j2] = *(const bf16x8*)((const char*)(Bs[buf]) + idx * 16); \
            }                                                                  \
            _Pragma("unroll")                                                  \
            for (int i = 0; i < 4; ++i)                                        \
                _Pragma("unroll")                                              \
                for (int j2 = 0; j2 < 4; ++j2)                                 \
                    acc[i][j2] = __builtin_amdgcn_mfma_f32_16x16x32_bf16(af[i], bfr[j2], acc[i][j2], 0, 0, 0); \
        }                                                                      \
    } while (0)

    STAGE(0, 0);     // -> buf0
    STAGE(1, 64);    // -> buf1   (16 loads in flight)

    #pragma unroll 1
    for (int kp = 0; kp < 4; ++kp) {       // K = 512 = 4 x (two 64-halves)
        const int ko = kp * 128;
        // ---- half A: buf0 (k = ko) ----
        asm volatile("s_waitcnt vmcnt(8)" ::: "memory");   // my buf0 loads done
        __builtin_amdgcn_s_barrier();                      // all waves ready
        __builtin_amdgcn_s_setprio(1);
        COMPUTE(0);
        __builtin_amdgcn_s_setprio(0);
        asm volatile("s_waitcnt lgkmcnt(0)" ::: "memory"); // my ds_reads of buf0 done
        __builtin_amdgcn_sched_barrier(0);
        __builtin_amdgcn_s_barrier();                      // all waves done reading buf0
        if (kp < 3) STAGE(0, ko + 128);                    // refill buf0 (in flight: 16)
        // ---- half B: buf1 (k = ko + 64) ----
        if (kp < 3) asm volatile("s_waitcnt vmcnt(8)" ::: "memory");
        else        asm volatile("s_waitcnt vmcnt(0)" ::: "memory");
        __builtin_amdgcn_s_barrier();
        __builtin_amdgcn_s_setprio(1);
        COMPUTE(1);
        __builtin_amdgcn_s_setprio(0);
        asm volatile("s_waitcnt lgkmcnt(0)" ::: "memory");
        __builtin_amdgcn_sched_barrier(0);
        __builtin_amdgcn_s_barrier();
        if (kp < 3) STAGE(1, ko + 192);
    }
#undef STAGE
#undef COMPUTE

    // epilogue: C/D layout col=l16 (n-dim), row=quad*4+reg (m-dim); write out[n*LDO+m]
    #pragma unroll
    for (int i = 0; i < 4; ++i) {
        const int mb = m0 + wm * 64 + i * 16 + quad * 4;
        f32x4 bb = {0.f, 0.f, 0.f, 0.f};
        if constexpr (BIAS) bb = *(const f32x4*)(bias + mb);
        #pragma unroll
        for (int j2 = 0; j2 < 4; ++j2) {
            const int n = n0 + wn * 64 + j2 * 16 + l16;
            f32x4 v = acc[i][j2];
            if constexpr (BIAS) v += bb;
            if constexpr (RELU) {
                v.x = v.x > 0.f ? v.x : 0.f;
                v.y = v.y > 0.f ? v.y : 0.f;
                v.z = v.z > 0.f ? v.z : 0.f;
                v.w = v.w > 0.f ? v.w : 0.f;
            }
            if constexpr (sizeof(OT) == 4) {
                *(f32x4*)((float*)out + (size_t)n * LDO + mb) = v;
            } else {
                u16x4 o;
                o.x = f2bf(v.x); o.y = f2bf(v.y); o.z = f2bf(v.z); o.w = f2bf(v.w);
                *(u16x4*)((unsigned short*)out + (size_t)n * LDO + mb) = o;
            }
        }
    }
}

extern "C" void kernel_launch(void* const* d_in, const int* in_sizes, int n_in,
                              void* d_out, int out_size, void* d_ws, size_t ws_size,
                              hipStream_t stream) {
    (void)in_sizes; (void)n_in; (void)out_size; (void)ws_size;
    const float* X   = (const float*)d_in[0];
    const float* adj = (const float*)d_in[1];
    const float* W0  = (const float*)d_in[2];
    const float* b0  = (const float*)d_in[3];
    const float* W1  = (const float*)d_in[4];
    const float* b1  = (const float*)d_in[5];
    const float* W2  = (const float*)d_in[6];
    const float* b2  = (const float*)d_in[7];
    float* out = (float*)d_out;

    // workspace layout (bf16): adjB | bufH (X/h, node-major) | tmpT (feat-major) | Wt x3
    char* ws = (char*)d_ws;
    const size_t SZ = 16777216;  // 32*512*512*2
    unsigned short* adjB = (unsigned short*)(ws);
    unsigned short* bufH = (unsigned short*)(ws + SZ);
    unsigned short* tmpT = (unsigned short*)(ws + 2 * SZ);
    unsigned short* Wt   = (unsigned short*)(ws + 3 * SZ);
    const unsigned short* W0t = Wt;
    const unsigned short* W1t = Wt + 262144;
    const unsigned short* W2t = Wt + 2 * 262144;

    prep_kernel<<<16384 + 768, 256, 0, stream>>>(X, adj, W0, W1, W2, bufH, adjB, Wt);

    const long BATCH = 512L * 512L;

    // layer 0: tmpT[e][node] = (h @ W0);  h = relu(adj @ tmp + b0) node-major
    gemm_abT_ct<512, 512, 16384, false, false, false, unsigned short>
        <<<512, 256, 0, stream>>>(bufH, W0t, tmpT, nullptr, 0, 0, 0);
    gemm_abT_ct<16384, 512, 512, true, true, true, unsigned short>
        <<<512, 256, 0, stream>>>(tmpT, adjB, bufH, b0, 512, BATCH, BATCH);
    // layer 1
    gemm_abT_ct<512, 512, 16384, false, false, false, unsigned short>
        <<<512, 256, 0, stream>>>(bufH, W1t, tmpT, nullptr, 0, 0, 0);
    gemm_abT_ct<16384, 512, 512, true, true, true, unsigned short>
        <<<512, 256, 0, stream>>>(tmpT, adjB, bufH, b1, 512, BATCH, BATCH);
    // layer 2 (no relu, fp32 out)
    gemm_abT_ct<512, 512, 16384, false, false, false, unsigned short>
        <<<512, 256, 0, stream>>>(bufH, W2t, tmpT, nullptr, 0, 0, 0);
    gemm_abT_ct<16384, 512, 512, true, false, true, float>
        <<<512, 256, 0, stream>>>(tmpT, adjB, out, b2, 512, BATCH, BATCH);
}

// Round 5
// 195.363 us; speedup vs baseline: 4.0021x; 1.0902x over previous
//
#include <hip/hip_runtime.h>
#include <stdint.h>

// ---------- types ----------
typedef __bf16 bf16x8 __attribute__((ext_vector_type(8)));
typedef float f32x4 __attribute__((ext_vector_type(4)));
typedef unsigned short u16x4 __attribute__((ext_vector_type(4)));

static __device__ __forceinline__ unsigned short f2bf(float f) {
    union { float f; unsigned u; } v; v.f = f;
    unsigned r = (v.u + 0x7FFFu + ((v.u >> 16) & 1u)) >> 16;  // RNE
    return (unsigned short)r;
}

// ---------- fused prep: convert X, convert adj, transpose W0/W1/W2 ----------
// grid.x = 8192 (X) + 8192 (adj) + 768 (W transpose tiles), 256 threads
__global__ void prep_kernel(const float* __restrict__ X,
                            const float* __restrict__ adj,
                            const float* __restrict__ W0,
                            const float* __restrict__ W1,
                            const float* __restrict__ W2,
                            unsigned short* __restrict__ bufH,
                            unsigned short* __restrict__ adjB,
                            unsigned short* __restrict__ Wt) {
    const int bid = blockIdx.x;
    const int t = threadIdx.x;
    if (bid < 16384) {
        const float* src = (bid < 8192) ? X : adj;
        unsigned short* dst = (bid < 8192) ? bufH : adjB;
        const int i = (bid & 8191) * 256 + t;
        f32x4 v = ((const f32x4*)src)[i];
        u16x4 o;
        o.x = f2bf(v.x); o.y = f2bf(v.y); o.z = f2bf(v.z); o.w = f2bf(v.w);
        ((u16x4*)dst)[i] = o;
    } else {
        const int wb = bid - 16384;          // 0..767
        const int z = wb >> 8;               // which W
        const int tile = wb & 255;           // 16x16 tiles of 32x32
        const float* W = (z == 0) ? W0 : (z == 1) ? W1 : W2;
        unsigned short* out = Wt + (size_t)z * (512 * 512);
        __shared__ float tileS[32][33];
        const int bx = (tile & 15) * 32, by = (tile >> 4) * 32;
        const int tx = t & 31, ty = t >> 5;  // 32 x 8
        #pragma unroll
        for (int r = 0; r < 32; r += 8)
            tileS[ty + r][tx] = W[(size_t)(by + ty + r) * 512 + (bx + tx)];
        __syncthreads();
        #pragma unroll
        for (int r = 0; r < 32; r += 8)
            out[(size_t)(bx + ty + r) * 512 + (by + tx)] = f2bf(tileS[tx][ty + r]);
    }
}

// ---------- GEMM: D[m][n] = sum_k A[m*LDA+k]*B[n*LDB+k]; writes out[n*LDO+m]
// 128x128 tile, BK=64 double-buffered, counted-vmcnt pipeline + XCD-affinity
// decode (both unchanged from round 4).
// NEW this round: coalesced epilogue. The MFMA fragment layout has l16 -> n,
// so direct stores scatter 64 lanes across 64 cache lines (stride LDO*2B).
// Instead: bias/relu'd fragments -> 128x128 LDS tile laid out [n][m] with
// 16B-chunk XOR swizzle (chunk ^= n&7, <=2-way banks), __syncthreads, then
// row-wise readback: 16 consecutive lanes cover one full 256B row segment ->
// dense global stores.
template<int LDA, int LDB, int LDO, bool BIAS, bool RELU, bool ADJ, typename OT>
__global__ __launch_bounds__(256, 2)
void gemm_abT_ct(const unsigned short* __restrict__ A,
                 const unsigned short* __restrict__ B,
                 OT* __restrict__ out, const float* __restrict__ bias,
                 long batchA, long batchB, long batchO) {
    __shared__ char SMEM[65536];
    unsigned short (*As)[8192] = (unsigned short (*)[8192])SMEM;            // 2 x 16 KB
    unsigned short (*Bs)[8192] = (unsigned short (*)[8192])(SMEM + 32768);  // 2 x 16 KB

    const int tid  = threadIdx.x;
    const int lane = tid & 63;
    const int wave = tid >> 6;
    const int quad = lane >> 4;
    const int l16  = lane & 15;
    const int wm   = wave & 1;
    const int wn   = wave >> 1;

    // ---- XCD-affinity decode (bijective over 512 blocks; 512 % 8 == 0) ----
    const int L = blockIdx.x;
    const int x = L & 7;        // XCD id (hw round-robin on linear block id)
    const int j = L >> 3;       // 0..63 within XCD
    int m0, n0;
    long z;
    if constexpr (ADJ) {
        z = x + 8 * (j >> 4);             // 4 z's per XCD
        const int t4 = j & 15;            // 16 tiles of this z
        m0 = (t4 & 3) * 128;
        n0 = (t4 >> 2) * 128;
    } else {
        z = 0;
        m0 = (x * 16 + (j >> 2)) * 128;   // XCD x owns 16 consecutive m-tiles
        n0 = (j & 3) * 128;
    }
    A   += (size_t)z * batchA;
    B   += (size_t)z * batchB;
    out += (size_t)z * batchO;

    const int trow8 = tid >> 3;                   // 0..31
    const int tpos8 = (tid & 7) ^ (trow8 & 7);    // r-independent swizzled pos
    const unsigned short* aG = A + (size_t)(m0 + trow8) * LDA + tpos8 * 8;
    const unsigned short* bG = B + (size_t)(n0 + trow8) * LDB + tpos8 * 8;

    f32x4 acc[4][4];
    #pragma unroll
    for (int i = 0; i < 4; ++i)
        #pragma unroll
        for (int j2 = 0; j2 < 4; ++j2) {
            f32x4 zz = {0.f, 0.f, 0.f, 0.f};
            acc[i][j2] = zz;
        }

#define STAGE(buf, ko)                                                         \
    do {                                                                       \
        char* aL = (char*)(As[buf]) + tid * 16;                                \
        char* bL = (char*)(Bs[buf]) + tid * 16;                                \
        _Pragma("unroll")                                                      \
        for (int r = 0; r < 4; ++r)                                            \
            __builtin_amdgcn_global_load_lds(                                  \
                (__attribute__((address_space(1))) void*)(uintptr_t)(aG + (size_t)(r * 32) * LDA + (ko)), \
                (__attribute__((address_space(3))) void*)(aL + r * 4096), 16, 0, 0); \
        _Pragma("unroll")                                                      \
        for (int r = 0; r < 4; ++r)                                            \
            __builtin_amdgcn_global_load_lds(                                  \
                (__attribute__((address_space(1))) void*)(uintptr_t)(bG + (size_t)(r * 32) * LDB + (ko)), \
                (__attribute__((address_space(3))) void*)(bL + r * 4096), 16, 0, 0); \
    } while (0)

#define COMPUTE(buf)                                                           \
    do {                                                                       \
        _Pragma("unroll")                                                      \
        for (int ks = 0; ks < 2; ++ks) {                                       \
            bf16x8 af[4], bfr[4];                                              \
            _Pragma("unroll")                                                  \
            for (int i = 0; i < 4; ++i) {                                      \
                const int row = wm * 64 + i * 16 + l16;                        \
                const int idx = row * 8 + ((ks * 4 + quad) ^ (row & 7));       \
                af[i] = *(const bf16x8*)((const char*)(As[buf]) + idx * 16);   \
            }                                                                  \
            _Pragma("unroll")                                                  \
            for (int j2 = 0; j2 < 4; ++j2) {                                   \
                const int row = wn * 64 + j2 * 16 + l16;                       \
                const int idx = row * 8 + ((ks * 4 + quad) ^ (row & 7));       \
                bfr[j2] = *(const bf16x8*)((const char*)(Bs[buf]) + idx * 16); \
            }                                                                  \
            _Pragma("unroll")                                                  \
            for (int i = 0; i < 4; ++i)                                        \
                _Pragma("unroll")                                              \
                for (int j2 = 0; j2 < 4; ++j2)                                 \
                    acc[i][j2] = __builtin_amdgcn_mfma_f32_16x16x32_bf16(af[i], bfr[j2], acc[i][j2], 0, 0, 0); \
        }                                                                      \
    } while (0)

    STAGE(0, 0);     // -> buf0
    STAGE(1, 64);    // -> buf1   (16 loads in flight)

    #pragma unroll 1
    for (int kp = 0; kp < 4; ++kp) {       // K = 512 = 4 x (two 64-halves)
        const int ko = kp * 128;
        // ---- half A: buf0 (k = ko) ----
        asm volatile("s_waitcnt vmcnt(8)" ::: "memory");   // my buf0 loads done
        __builtin_amdgcn_s_barrier();                      // all waves ready
        __builtin_amdgcn_s_setprio(1);
        COMPUTE(0);
        __builtin_amdgcn_s_setprio(0);
        asm volatile("s_waitcnt lgkmcnt(0)" ::: "memory"); // my ds_reads of buf0 done
        __builtin_amdgcn_sched_barrier(0);
        __builtin_amdgcn_s_barrier();                      // all waves done reading buf0
        if (kp < 3) STAGE(0, ko + 128);                    // refill buf0 (in flight: 16)
        // ---- half B: buf1 (k = ko + 64) ----
        if (kp < 3) asm volatile("s_waitcnt vmcnt(8)" ::: "memory");
        else        asm volatile("s_waitcnt vmcnt(0)" ::: "memory");
        __builtin_amdgcn_s_barrier();
        __builtin_amdgcn_s_setprio(1);
        COMPUTE(1);
        __builtin_amdgcn_s_setprio(0);
        asm volatile("s_waitcnt lgkmcnt(0)" ::: "memory");
        __builtin_amdgcn_sched_barrier(0);
        __builtin_amdgcn_s_barrier();
        if (kp < 3) STAGE(1, ko + 192);
    }
#undef STAGE
#undef COMPUTE

    // ---- coalesced epilogue via LDS transpose (K-loop ended with barrier,
    // so SMEM is free to reuse) ----
    if constexpr (sizeof(OT) == 2) {
        // bf16 tile [n=128][m=128], 256B rows = 16 x 16B chunks, chunk ^= n&7
        unsigned short* T = (unsigned short*)SMEM;   // 32 KB
        #pragma unroll
        for (int i = 0; i < 4; ++i) {
            const int mloc = wm * 64 + i * 16 + quad * 4;
            const int mb = m0 + mloc;
            f32x4 bb = {0.f, 0.f, 0.f, 0.f};
            if constexpr (BIAS) bb = *(const f32x4*)(bias + mb);
            const int ch  = mloc >> 3;           // 16B chunk index 0..15
            const int sub = (mloc & 7) * 2;      // byte offset within chunk (0/8)
            #pragma unroll
            for (int j2 = 0; j2 < 4; ++j2) {
                const int nloc = wn * 64 + j2 * 16 + l16;
                f32x4 v = acc[i][j2];
                if constexpr (BIAS) v += bb;
                if constexpr (RELU) {
                    v.x = v.x > 0.f ? v.x : 0.f;
                    v.y = v.y > 0.f ? v.y : 0.f;
                    v.z = v.z > 0.f ? v.z : 0.f;
                    v.w = v.w > 0.f ? v.w : 0.f;
                }
                u16x4 o;
                o.x = f2bf(v.x); o.y = f2bf(v.y); o.z = f2bf(v.z); o.w = f2bf(v.w);
                *(u16x4*)((char*)T + nloc * 256 + ((ch ^ (nloc & 7)) << 4) + sub) = o;
            }
        }
        __syncthreads();
        #pragma unroll
        for (int it = 0; it < 8; ++it) {
            const int n  = (tid >> 4) + 16 * it;   // 0..127
            const int cc = tid & 15;               // chunk in row: 16 lanes = 256B dense
            f32x4 d = *(const f32x4*)((const char*)T + n * 256 + ((cc ^ (n & 7)) << 4));
            *(f32x4*)((unsigned short*)out + (size_t)(n0 + n) * LDO + m0 + cc * 8) = d;
        }
    } else {
        // f32 tile [n=128][m=128], 512B rows = 32 x 16B chunks, chunk ^= n&7 (64 KB)
        float* T = (float*)SMEM;
        #pragma unroll
        for (int i = 0; i < 4; ++i) {
            const int mloc = wm * 64 + i * 16 + quad * 4;
            const int mb = m0 + mloc;
            f32x4 bb = {0.f, 0.f, 0.f, 0.f};
            if constexpr (BIAS) bb = *(const f32x4*)(bias + mb);
            const int ch = mloc >> 2;            // 16B chunk index 0..31
            #pragma unroll
            for (int j2 = 0; j2 < 4; ++j2) {
                const int nloc = wn * 64 + j2 * 16 + l16;
                f32x4 v = acc[i][j2];
                if constexpr (BIAS) v += bb;
                if constexpr (RELU) {
                    v.x = v.x > 0.f ? v.x : 0.f;
                    v.y = v.y > 0.f ? v.y : 0.f;
                    v.z = v.z > 0.f ? v.z : 0.f;
                    v.w = v.w > 0.f ? v.w : 0.f;
                }
                *(f32x4*)((char*)T + nloc * 512 + ((ch ^ (nloc & 7)) << 4)) = v;
            }
        }
        __syncthreads();
        #pragma unroll
        for (int it = 0; it < 16; ++it) {
            const int n  = (tid >> 4) + 16 * (it >> 1);      // 0..127
            const int cc = (tid & 15) + 16 * (it & 1);       // 0..31
            f32x4 d = *(const f32x4*)((const char*)T + n * 512 + ((cc ^ (n & 7)) << 4));
            *(f32x4*)((float*)out + (size_t)(n0 + n) * LDO + m0 + cc * 4) = d;
        }
    }
}

extern "C" void kernel_launch(void* const* d_in, const int* in_sizes, int n_in,
                              void* d_out, int out_size, void* d_ws, size_t ws_size,
                              hipStream_t stream) {
    (void)in_sizes; (void)n_in; (void)out_size; (void)ws_size;
    const float* X   = (const float*)d_in[0];
    const float* adj = (const float*)d_in[1];
    const float* W0  = (const float*)d_in[2];
    const float* b0  = (const float*)d_in[3];
    const float* W1  = (const float*)d_in[4];
    const float* b1  = (const float*)d_in[5];
    const float* W2  = (const float*)d_in[6];
    const float* b2  = (const float*)d_in[7];
    float* out = (float*)d_out;

    // workspace layout (bf16): adjB | bufH (X/h, node-major) | tmpT (feat-major) | Wt x3
    char* ws = (char*)d_ws;
    const size_t SZ = 16777216;  // 32*512*512*2
    unsigned short* adjB = (unsigned short*)(ws);
    unsigned short* bufH = (unsigned short*)(ws + SZ);
    unsigned short* tmpT = (unsigned short*)(ws + 2 * SZ);
    unsigned short* Wt   = (unsigned short*)(ws + 3 * SZ);
    const unsigned short* W0t = Wt;
    const unsigned short* W1t = Wt + 262144;
    const unsigned short* W2t = Wt + 2 * 262144;

    prep_kernel<<<16384 + 768, 256, 0, stream>>>(X, adj, W0, W1, W2, bufH, adjB, Wt);

    const long BATCH = 512L * 512L;

    // layer 0: tmpT[e][node] = (h @ W0);  h = relu(adj @ tmp + b0) node-major
    gemm_abT_ct<512, 512, 16384, false, false, false, unsigned short>
        <<<512, 256, 0, stream>>>(bufH, W0t, tmpT, nullptr, 0, 0, 0);
    gemm_abT_ct<16384, 512, 512, true, true, true, unsigned short>
        <<<512, 256, 0, stream>>>(tmpT, adjB, bufH, b0, 512, BATCH, BATCH);
    // layer 1
    gemm_abT_ct<512, 512, 16384, false, false, false, unsigned short>
        <<<512, 256, 0, stream>>>(bufH, W1t, tmpT, nullptr, 0, 0, 0);
    gemm_abT_ct<16384, 512, 512, true, true, true, unsigned short>
        <<<512, 256, 0, stream>>>(tmpT, adjB, bufH, b1, 512, BATCH, BATCH);
    // layer 2 (no relu, fp32 out)
    gemm_abT_ct<512, 512, 16384, false, false, false, unsigned short>
        <<<512, 256, 0, stream>>>(bufH, W2t, tmpT, nullptr, 0, 0, 0);
    gemm_abT_ct<16384, 512, 512, true, false, true, float>
        <<<512, 256, 0, stream>>>(tmpT, adjB, out, b2, 512, BATCH, BATCH);
}